// Round 6
// baseline (30.942 us; speedup 1.0000x reference)
//
#include <hip/hip_runtime.h>

// One-sided Chamfer: out[b][m] = min_n || point[b][m] - input[b][n] ||^2
// B=2, N=8192, M=8192, D=3, fp32.
//
// K0 (prep): repack input -> refs4[b*N+n] = (x, y, z, 0.5*|q|^2) in d_ws,
//            and init out[o] = +inf bits.
// K1 (main): NO LDS. Ref stream read via per-lane VMEM broadcast loads
//            (all 64 lanes same address -> 1 coalesced L2-hot request).
//            R5 showed the compiler scalarizes provably-uniform addresses
//            to s_load (SMEM latency + v_mov tax); we defeat uniformity
//            analysis with an empty asm on a zero so it emits
//            global_load_dwordx4 with normal compiler vmcnt scheduling.
//            Pipe budget/CU @16 waves: VALU ~14.3K cyc, VMEM issue ~8.2K,
//            LDS 0 -> VALU-bound (~7 us).
//   t = 0.5*|q|^2 - p.q (3 FMA/pair, min3-fused merge), exact atomicMin
//   on uint bit pattern (d2 >= 0 -> order isomorphic).
// Shape proven in r1/r2: BQ=256, QPT=4, NSPLIT=64 -> 1024 blocks, 4 w/SIMD.

constexpr int BB = 2;
constexpr int NN = 8192;
constexpr int MM = 8192;

constexpr int BQ = 256;            // threads per block (main)
constexpr int QPT = 4;             // queries per thread
constexpr int QBLK = BQ * QPT;     // 1024 queries per block
constexpr int NSPLIT = 64;         // N slices -> 1024 blocks (4/CU)
constexpr int SLICE = NN / NSPLIT; // 128 refs per slice
constexpr int BM = BB * MM;        // 16384 outputs (== BB*NN)

__global__ __launch_bounds__(256) void chamfer_prep_kernel(
    const float* __restrict__ input,   // [B, N, 3]
    float4* __restrict__ refs4,        // [B*N] packed refs in d_ws
    unsigned int* __restrict__ out)    // [B*M] init to +inf bits
{
    const int i = blockIdx.x * 256 + threadIdx.x;   // 0 .. BM-1
    const float x = input[i * 3 + 0];
    const float y = input[i * 3 + 1];
    const float z = input[i * 3 + 2];
    refs4[i] = make_float4(x, y, z, 0.5f * (x * x + y * y + z * z));
    out[i] = 0x7F800000u;  // +inf
}

__global__ __launch_bounds__(BQ) void chamfer_main_kernel(
    const float4* __restrict__ refs4,  // [B*N]
    const float* __restrict__ point,   // [B, M, 3]
    unsigned int* __restrict__ out)    // [B*M], pre-init +inf
{
    const int b   = blockIdx.z;
    const int m0  = blockIdx.x * QBLK;
    const int tid = threadIdx.x;

    // --- this thread's queries in registers (negated for FMA) ---
    const float* ptb = point + (size_t)b * MM * 3;
    float nx[QPT], ny[QPT], nz[QPT], p2[QPT], tmin[QPT];
#pragma unroll
    for (int q = 0; q < QPT; ++q) {
        const int m = m0 + q * BQ + tid;
        const float x = ptb[m * 3 + 0];
        const float y = ptb[m * 3 + 1];
        const float z = ptb[m * 3 + 2];
        nx[q] = -x; ny[q] = -y; nz[q] = -z;
        p2[q] = x * x + y * y + z * z;
        tmin[q] = 3.0e38f;
    }

    // --- defeat uniformity analysis: zero the compiler can't prove zero ---
    // Forces per-lane VGPR addressing -> global_load_dwordx4 broadcast
    // (not s_load), while keeping compiler-managed vmcnt scheduling.
    unsigned int zero = 0;
    asm volatile("" : "+v"(zero));

    const float4* rp = refs4 + (size_t)b * NN + (size_t)blockIdx.y * SLICE
                             + zero;

    // --- inner loop: 2 refs/iter via VMEM broadcast; min3-fused merge ---
#pragma unroll 4
    for (int j = 0; j < SLICE; j += 2) {
        const float4 r0 = rp[j];
        const float4 r1 = rp[j + 1];
#pragma unroll
        for (int q = 0; q < QPT; ++q) {
            float s0 = fmaf(nx[q], r0.x, r0.w);
            s0 = fmaf(ny[q], r0.y, s0);
            s0 = fmaf(nz[q], r0.z, s0);
            float s1 = fmaf(nx[q], r1.x, r1.w);
            s1 = fmaf(ny[q], r1.y, s1);
            s1 = fmaf(nz[q], r1.z, s1);
            tmin[q] = fminf(fminf(tmin[q], s0), s1);  // -> v_min3_f32
        }
    }

    // --- exact merge across N-slices: atomicMin on uint bit pattern ---
    unsigned int* outb = out + (size_t)b * MM;
#pragma unroll
    for (int q = 0; q < QPT; ++q) {
        const int m = m0 + q * BQ + tid;
        const float d2 = fmaxf(fmaf(2.0f, tmin[q], p2[q]), 0.0f);
        atomicMin(outb + m, __float_as_uint(d2));
    }
}

extern "C" void kernel_launch(void* const* d_in, const int* in_sizes, int n_in,
                              void* d_out, int out_size, void* d_ws, size_t ws_size,
                              hipStream_t stream) {
    const float* input = (const float*)d_in[0];   // [B, N, 3]
    const float* point = (const float*)d_in[1];   // [B, M, 3]
    unsigned int* out  = (unsigned int*)d_out;    // [B, M] as uint bits
    float4* refs4      = (float4*)d_ws;           // 256 KB scratch

    chamfer_prep_kernel<<<dim3(BM / 256), dim3(256), 0, stream>>>(input, refs4, out);

    dim3 grid(MM / QBLK, NSPLIT, BB);
    chamfer_main_kernel<<<grid, dim3(BQ), 0, stream>>>(refs4, point, out);
}

// Round 7
// 24.289 us; speedup vs baseline: 1.2739x; 1.2739x over previous
//
#include <hip/hip_runtime.h>

// One-sided Chamfer: out[b][m] = min_n || point[b][m] - input[b][n] ||^2
// B=2, N=8192, M=8192, D=3, fp32.
//
// SINGLE-DISPATCH, TRANSPOSED decomposition:
//   - Each wave owns K=4 queries, kept as wave-uniform register values.
//   - Each LANE streams its own distinct refs (coalesced global_load_dwordx3,
//     L1/L2-hot). NO broadcast pipe: no LDS staging (R1/R2: ~10us LDS bound),
//     no s_load stream (R5), no VMEM broadcast (R6).
//   - t' = |r|^2 - 2 q.r per pair (query coords pre-doubled, |r|^2 on the
//     fly amortized over 4 queries); per-lane running min; final 6-step
//     __shfl_xor min-reduce (24 ds-ops/wave total -- negligible) and a
//     plain store per query. No ws, no atomics, no init, no merge kernel.
//   - d2 = max(t'min + |p|^2, 0).
// Geometry: 1024 blocks x 256 (4 waves) = 4 blocks/CU (proven best shape).
// __syncthreads every CHUNK refs keeps a block's waves in one L1 window.

constexpr int BB = 2;
constexpr int NN = 8192;
constexpr int MM = 8192;

constexpr int K    = 4;               // queries per wave
constexpr int WPB  = 4;               // waves per block
constexpr int BQ   = WPB * 64;        // 256 threads
constexpr int QPB  = WPB * K;         // 16 queries per block
constexpr int GRID = (BB * MM) / QPB; // 1024 blocks
constexpr int CHUNK = 512;            // refs per sync window (6 KB)

struct F3 { float x, y, z; };

__global__ __launch_bounds__(BQ) void chamfer_kernel(
    const float* __restrict__ input,   // [B, N, 3]
    const float* __restrict__ point,   // [B, M, 3]
    float* __restrict__ out)           // [B*M]
{
    const int tid  = threadIdx.x;
    const int lane = tid & 63;
    const int wid  = tid >> 6;
    const int W    = blockIdx.x * WPB + wid;  // global wave id
    const int o0   = W * K;                   // first flat query index
    const int b    = o0 / MM;                 // batch (uniform per block)

    // --- K wave-uniform queries into registers (pre-doubled, negated) ---
    const float* ptb = point + (size_t)o0 * 3;
    float nx2[K], ny2[K], nz2[K], p2[K], tmin[K];
#pragma unroll
    for (int q = 0; q < K; ++q) {
        const float x = ptb[q * 3 + 0];
        const float y = ptb[q * 3 + 1];
        const float z = ptb[q * 3 + 2];
        nx2[q] = -2.0f * x; ny2[q] = -2.0f * y; nz2[q] = -2.0f * z;
        p2[q]  = fmaf(z, z, fmaf(y, y, x * x));
        tmin[q] = 3.0e38f;
    }

    const F3* inb = (const F3*)(input + (size_t)b * NN * 3);

    // --- per-lane ref stream: 2 refs/lane/iter, coalesced dwordx3 loads ---
    for (int c = 0; c < NN; c += CHUNK) {
#pragma unroll 4
        for (int j = 0; j < CHUNK; j += 128) {
            const int n0 = c + j + lane;
            const F3 r0 = inb[n0];
            const F3 r1 = inb[n0 + 64];
            const float h0 = fmaf(r0.z, r0.z, fmaf(r0.y, r0.y, r0.x * r0.x));
            const float h1 = fmaf(r1.z, r1.z, fmaf(r1.y, r1.y, r1.x * r1.x));
#pragma unroll
            for (int q = 0; q < K; ++q) {
                float s0 = fmaf(nx2[q], r0.x, h0);
                s0 = fmaf(ny2[q], r0.y, s0);
                s0 = fmaf(nz2[q], r0.z, s0);
                float s1 = fmaf(nx2[q], r1.x, h1);
                s1 = fmaf(ny2[q], r1.y, s1);
                s1 = fmaf(nz2[q], r1.z, s1);
                tmin[q] = fminf(fminf(tmin[q], s0), s1);  // -> v_min3_f32
            }
        }
        __syncthreads();  // keep block's 4 waves in one L1 window
    }

    // --- 64-lane min-reduce per query (6 shuffles), then one plain store ---
#pragma unroll
    for (int q = 0; q < K; ++q) {
        float v = tmin[q];
#pragma unroll
        for (int m = 1; m < 64; m <<= 1)
            v = fminf(v, __shfl_xor(v, m, 64));
        if (lane == q)
            out[o0 + q] = fmaxf(v + p2[q], 0.0f);
    }
}

extern "C" void kernel_launch(void* const* d_in, const int* in_sizes, int n_in,
                              void* d_out, int out_size, void* d_ws, size_t ws_size,
                              hipStream_t stream) {
    const float* input = (const float*)d_in[0];   // [B, N, 3]
    const float* point = (const float*)d_in[1];   // [B, M, 3]
    float* out = (float*)d_out;                   // [B, M]

    chamfer_kernel<<<dim3(GRID), dim3(BQ), 0, stream>>>(input, point, out);
}

// Round 8
// 20.777 us; speedup vs baseline: 1.4893x; 1.1690x over previous
//
#include <hip/hip_runtime.h>

// One-sided Chamfer via MFMA: out[b][m] = min_n ||p_m - q_n||^2.
// B=2, N=M=8192, D=3, fp32 in/out.
//
// cross+|q|^2 computed by ONE v_mfma_f32_32x32x16_bf16 per 32x32 tile using
// fp32->bf16 hi/lo splits packed into K slots:
//   A row m : [-2ph.x,-2ph.y,-2ph.z, -2pl.x,-2pl.y,-2pl.z, -2ph.x,-2ph.y |
//              -2ph.z, 1, 1, 0,0,0,0,0]
//   B col n : [ qh.x,  qh.y,  qh.z,   qh.x,  qh.y,  qh.z,   ql.x,  ql.y |
//               ql.z, q2h, q2l, 0,0,0,0,0]
//   acc = q2 - 2(ph.qh + pl.qh + ph.ql)   (drops pl.ql ~ 1e-5)
//   d2  = max(min_tiles(acc) + p2_fp32, 0)
// Per-wave: 32 queries fixed in A-frag; 32 tiles over its 1024-ref slice;
// B-frags staged once per block in LDS (32 KB). 4x fewer ds_read_b128 than
// the VALU formulation (131K tiles vs 524K reads) -> LDS ~2.5us, MFMA ~0.1us.
// Merge over NS=8 slices via ws + small min-reduce kernel.
//
// C/D layout (verified m74/m101): col=lane&31, row=(r&3)+8*(r>>2)+4*(lane>>5).
// A/B layout (assumed std gfx950): row/col=lane&31, k=(lane>>5)*8+i.

typedef __attribute__((ext_vector_type(8)))  short  short8;
typedef __attribute__((ext_vector_type(16))) float  f32x16;

constexpr int BB = 2;
constexpr int NN = 8192;
constexpr int MM = 8192;
constexpr int BM = BB * MM;

constexpr int QB = 128;          // queries per block (4 waves x 32)
constexpr int NS = 8;            // N slices
constexpr int SL = NN / NS;      // 1024 refs per slice
constexpr int NT = SL / 32;      // 32 n-tiles per slice

__device__ inline unsigned short f2bf(float f) {          // RNE fp32->bf16
    unsigned u = __float_as_uint(f);
    return (unsigned short)((u + 0x7FFFu + ((u >> 16) & 1u)) >> 16);
}
__device__ inline float bf2f(unsigned short h) {
    return __uint_as_float((unsigned)h << 16);
}

__global__ __launch_bounds__(256) void chamfer_mfma_kernel(
    const float* __restrict__ input,   // [B, N, 3]
    const float* __restrict__ point,   // [B, M, 3]
    float* __restrict__ ws)            // [NS, B*M] partial d2
{
    __shared__ short8 frag[NT * 64];   // 32 KB of pre-swizzled B-frags

    const int tid  = threadIdx.x;
    const int lane = tid & 63;
    const int w    = tid >> 6;
    const int b    = blockIdx.z;
    const int qb0  = blockIdx.x * QB;
    const int n0   = blockIdx.y * SL;

    // ---- stage B-fragments: entry e = (tile t, frag-lane l) ----
    const float* inb = input + (size_t)b * NN * 3;
    for (int e = tid; e < NT * 64; e += 256) {
        const int t = e >> 6, l = e & 63, col = l & 31;
        const int n = n0 + t * 32 + col;
        const float x = inb[n * 3 + 0];
        const float y = inb[n * 3 + 1];
        const float z = inb[n * 3 + 2];
        const float q2 = fmaf(z, z, fmaf(y, y, x * x));
        const unsigned short hx = f2bf(x), hy = f2bf(y), hz = f2bf(z);
        const unsigned short lx = f2bf(x - bf2f(hx));
        const unsigned short ly = f2bf(y - bf2f(hy));
        const unsigned short lz = f2bf(z - bf2f(hz));
        const unsigned short q2h = f2bf(q2);
        const unsigned short q2l = f2bf(q2 - bf2f(q2h));
        short8 v;
        if (l < 32) {  // k0..7
            v[0] = (short)hx; v[1] = (short)hy; v[2] = (short)hz; v[3] = (short)hx;
            v[4] = (short)hy; v[5] = (short)hz; v[6] = (short)lx; v[7] = (short)ly;
        } else {       // k8..15
            v[0] = (short)lz; v[1] = (short)q2h; v[2] = (short)q2l; v[3] = 0;
            v[4] = 0; v[5] = 0; v[6] = 0; v[7] = 0;
        }
        frag[e] = v;
    }

    // ---- A-fragment: this lane's query (row = lane&31) ----
    const int row = lane & 31, h = lane >> 5;
    const int m   = qb0 + w * 32 + row;
    const float* pp = point + ((size_t)b * MM + m) * 3;
    const float x = pp[0], y = pp[1], z = pp[2];
    const float p2 = fmaf(z, z, fmaf(y, y, x * x));
    const float hxf = bf2f(f2bf(x)), hyf = bf2f(f2bf(y)), hzf = bf2f(f2bf(z));
    const unsigned short ahx = f2bf(-2.0f * hxf);
    const unsigned short ahy = f2bf(-2.0f * hyf);
    const unsigned short ahz = f2bf(-2.0f * hzf);
    const unsigned short alx = f2bf(-2.0f * (x - hxf));
    const unsigned short aly = f2bf(-2.0f * (y - hyf));
    const unsigned short alz = f2bf(-2.0f * (z - hzf));
    const short one = (short)0x3F80;  // bf16 1.0
    short8 a;
    if (h == 0) {
        a[0] = (short)ahx; a[1] = (short)ahy; a[2] = (short)ahz; a[3] = (short)alx;
        a[4] = (short)aly; a[5] = (short)alz; a[6] = (short)ahx; a[7] = (short)ahy;
    } else {
        a[0] = (short)ahz; a[1] = one; a[2] = one; a[3] = 0;
        a[4] = 0; a[5] = 0; a[6] = 0; a[7] = 0;
    }

    __syncthreads();

    // ---- main loop: 1 ds_read_b128 + 1 MFMA + 16 min per tile ----
    f32x16 run, zero;
#pragma unroll
    for (int i = 0; i < 16; ++i) { run[i] = 3.0e38f; zero[i] = 0.0f; }

#pragma unroll 2
    for (int t = 0; t < NT; ++t) {
        const short8 bf = frag[t * 64 + lane];
        const f32x16 d = __builtin_amdgcn_mfma_f32_32x32x16_bf16(a, bf, zero, 0, 0, 0);
#pragma unroll
        for (int i = 0; i < 16; ++i) run[i] = fminf(run[i], d[i]);
    }

    // ---- reduce across cols (32 lanes per half), add p2, store partial ----
    float* wsy = ws + (size_t)blockIdx.y * BM + (size_t)b * MM;
#pragma unroll
    for (int r = 0; r < 16; ++r) {
        float v = run[r];
#pragma unroll
        for (int msk = 1; msk < 32; msk <<= 1)
            v = fminf(v, __shfl_xor(v, msk, 64));
        const int rr = (r & 3) + 8 * (r >> 2) + 4 * h;  // output row of reg r
        const float pr = __shfl(p2, rr, 64);            // p2 lives in lane rr
        const float d2 = fmaxf(v + pr, 0.0f);
        if (row == rr) wsy[qb0 + w * 32 + rr] = d2;
    }
}

// out[o] = min over NS slices of ws[y][o]
__global__ __launch_bounds__(256) void chamfer_reduce_kernel(
    const float* __restrict__ ws, float* __restrict__ out)
{
    const int o = blockIdx.x * 256 + threadIdx.x;
    float acc = ws[o];
#pragma unroll
    for (int y = 1; y < NS; ++y)
        acc = fminf(acc, ws[(size_t)y * BM + o]);
    out[o] = acc;
}

extern "C" void kernel_launch(void* const* d_in, const int* in_sizes, int n_in,
                              void* d_out, int out_size, void* d_ws, size_t ws_size,
                              hipStream_t stream) {
    const float* input = (const float*)d_in[0];   // [B, N, 3]
    const float* point = (const float*)d_in[1];   // [B, M, 3]
    float* out = (float*)d_out;                   // [B, M]
    float* ws  = (float*)d_ws;                    // [NS, B*M] = 512 KB

    dim3 grid1(MM / QB, NS, BB);
    chamfer_mfma_kernel<<<grid1, dim3(256), 0, stream>>>(input, point, ws);

    chamfer_reduce_kernel<<<dim3(BM / 256), dim3(256), 0, stream>>>(ws, out);
}

// Round 9
// 16.444 us; speedup vs baseline: 1.8817x; 1.2635x over previous
//
#include <hip/hip_runtime.h>

// One-sided Chamfer via MFMA: out[b][m] = min_n ||p_m - q_n||^2.
// B=2, N=M=8192, D=3, fp32 in/out.
//
// TRANSPOSED MFMA assignment (vs R8): refs in A (rows), queries in B (cols).
//   D[row=ref][col=query] = q2 - 2 p.q  via bf16 hi/lo splits in K slots:
//     A row (ref q):   [qh.x,qh.y,qh.z, qh.x,qh.y,qh.z, ql.x,ql.y |
//                       ql.z, q2h, q2l, 0,0,0,0,0]
//     B col (query p): [-2ph.x,-2ph.y,-2ph.z, -2pl.x,-2pl.y,-2pl.z,
//                       -2ph.x,-2ph.y | -2ph.z, 1, 1, 0,0,0,0,0]
//   (drops pl.ql ~ 1e-5; R8 measured absmax 0.002 << 0.047 threshold)
// Why: min is over refs = REGISTER dimension now. Per tile: register
// min3-tree (~8 VALU) accumulating a scalar tmin/lane; epilogue is ONE
// shfl_xor(32) + ONE store (R8 burned ~96 shuffle DS-ops/wave = ~3.8us/CU
// reducing across lanes). p2 is per-lane (col) -- no p2 shuffles either.
// Layout relations identical to R8's validated kernel (contents swapped):
//   A: row=lane&31, k=(lane>>5)*8+i | B: col=lane&31, same k
//   C/D: col=lane&31, row=(r&3)+8*(r>>2)+4*(lane>>5)   [m74/m101]
// Merge over NS=8 slices via ws + small min-reduce kernel (proven R2 path).

typedef __attribute__((ext_vector_type(8)))  short  short8;
typedef __attribute__((ext_vector_type(16))) float  f32x16;

constexpr int BB = 2;
constexpr int NN = 8192;
constexpr int MM = 8192;
constexpr int BM = BB * MM;

constexpr int QB = 128;          // queries per block (4 waves x 32)
constexpr int NS = 8;            // N slices
constexpr int SL = NN / NS;      // 1024 refs per slice
constexpr int NT = SL / 32;      // 32 ref-tiles per slice

__device__ inline unsigned short f2bf(float f) {          // RNE fp32->bf16
    unsigned u = __float_as_uint(f);
    return (unsigned short)((u + 0x7FFFu + ((u >> 16) & 1u)) >> 16);
}
__device__ inline float bf2f(unsigned short h) {
    return __uint_as_float((unsigned)h << 16);
}

__global__ __launch_bounds__(256) void chamfer_mfma_kernel(
    const float* __restrict__ input,   // [B, N, 3]  (refs q)
    const float* __restrict__ point,   // [B, M, 3]  (queries p)
    float* __restrict__ ws)            // [NS, B*M] partial d2
{
    __shared__ short8 frag[NT * 64];   // 32 KB pre-swizzled A-frags (refs)

    const int tid  = threadIdx.x;
    const int lane = tid & 63;
    const int w    = tid >> 6;
    const int b    = blockIdx.z;
    const int qb0  = blockIdx.x * QB;
    const int n0   = blockIdx.y * SL;

    // ---- stage A-fragments (refs): entry e = (tile t, frag-lane l) ----
    const float* inb = input + (size_t)b * NN * 3;
    for (int e = tid; e < NT * 64; e += 256) {
        const int t = e >> 6, l = e & 63;
        const int n = n0 + t * 32 + (l & 31);
        const float x = inb[n * 3 + 0];
        const float y = inb[n * 3 + 1];
        const float z = inb[n * 3 + 2];
        const float q2 = fmaf(z, z, fmaf(y, y, x * x));
        const unsigned short hx = f2bf(x), hy = f2bf(y), hz = f2bf(z);
        const unsigned short lx = f2bf(x - bf2f(hx));
        const unsigned short ly = f2bf(y - bf2f(hy));
        const unsigned short lz = f2bf(z - bf2f(hz));
        const unsigned short q2h = f2bf(q2);
        const unsigned short q2l = f2bf(q2 - bf2f(q2h));
        short8 v;
        if ((l >> 5) == 0) {  // k0..7
            v[0] = (short)hx; v[1] = (short)hy; v[2] = (short)hz; v[3] = (short)hx;
            v[4] = (short)hy; v[5] = (short)hz; v[6] = (short)lx; v[7] = (short)ly;
        } else {              // k8..15
            v[0] = (short)lz; v[1] = (short)q2h; v[2] = (short)q2l; v[3] = 0;
            v[4] = 0; v[5] = 0; v[6] = 0; v[7] = 0;
        }
        frag[e] = v;
    }

    // ---- B-fragment: this lane's query (col = lane&31) ----
    const int col = lane & 31, h = lane >> 5;
    const int m   = qb0 + w * 32 + col;
    const float* pp = point + ((size_t)b * MM + m) * 3;
    const float x = pp[0], y = pp[1], z = pp[2];
    const float p2 = fmaf(z, z, fmaf(y, y, x * x));
    const float hxf = bf2f(f2bf(x)), hyf = bf2f(f2bf(y)), hzf = bf2f(f2bf(z));
    const unsigned short bhx = f2bf(-2.0f * hxf);
    const unsigned short bhy = f2bf(-2.0f * hyf);
    const unsigned short bhz = f2bf(-2.0f * hzf);
    const unsigned short blx = f2bf(-2.0f * (x - hxf));
    const unsigned short bly = f2bf(-2.0f * (y - hyf));
    const unsigned short blz = f2bf(-2.0f * (z - hzf));
    const short one = (short)0x3F80;  // bf16 1.0
    short8 bq;
    if (h == 0) {
        bq[0] = (short)bhx; bq[1] = (short)bhy; bq[2] = (short)bhz; bq[3] = (short)blx;
        bq[4] = (short)bly; bq[5] = (short)blz; bq[6] = (short)bhx; bq[7] = (short)bhy;
    } else {
        bq[0] = (short)bhz; bq[1] = one; bq[2] = one; bq[3] = 0;
        bq[4] = 0; bq[5] = 0; bq[6] = 0; bq[7] = 0;
    }

    __syncthreads();

    // ---- main loop: 1 ds_read_b128 + 1 MFMA + register min3-tree/tile ----
    f32x16 zero;
#pragma unroll
    for (int i = 0; i < 16; ++i) zero[i] = 0.0f;
    float tmin = 3.0e38f;

#pragma unroll 2
    for (int t = 0; t < NT; ++t) {
        const short8 af = frag[t * 64 + lane];
        const f32x16 d = __builtin_amdgcn_mfma_f32_32x32x16_bf16(af, bq, zero, 0, 0, 0);
        // 16 refs (register dim) -> scalar, min3-fusable tree
        const float m0 = fminf(fminf(d[0],  d[1]),  d[2]);
        const float m1 = fminf(fminf(d[3],  d[4]),  d[5]);
        const float m2 = fminf(fminf(d[6],  d[7]),  d[8]);
        const float m3 = fminf(fminf(d[9],  d[10]), d[11]);
        const float m4 = fminf(fminf(d[12], d[13]), d[14]);
        const float r0 = fminf(fminf(m0, m1), d[15]);
        const float r1 = fminf(fminf(m2, m3), m4);
        tmin = fminf(fminf(tmin, r0), r1);
    }

    // ---- epilogue: fold other row-half, add p2, one store per query ----
    tmin = fminf(tmin, __shfl_xor(tmin, 32, 64));
    if (h == 0) {
        float* wsy = ws + (size_t)blockIdx.y * BM + (size_t)b * MM;
        wsy[m] = fmaxf(tmin + p2, 0.0f);
    }
}

// out[o] = min over NS slices of ws[y][o]
__global__ __launch_bounds__(256) void chamfer_reduce_kernel(
    const float* __restrict__ ws, float* __restrict__ out)
{
    const int o = blockIdx.x * 256 + threadIdx.x;
    float acc = ws[o];
#pragma unroll
    for (int y = 1; y < NS; ++y)
        acc = fminf(acc, ws[(size_t)y * BM + o]);
    out[o] = acc;
}

extern "C" void kernel_launch(void* const* d_in, const int* in_sizes, int n_in,
                              void* d_out, int out_size, void* d_ws, size_t ws_size,
                              hipStream_t stream) {
    const float* input = (const float*)d_in[0];   // [B, N, 3]
    const float* point = (const float*)d_in[1];   // [B, M, 3]
    float* out = (float*)d_out;                   // [B, M]
    float* ws  = (float*)d_ws;                    // [NS, B*M] = 512 KB

    dim3 grid1(MM / QB, NS, BB);
    chamfer_mfma_kernel<<<grid1, dim3(256), 0, stream>>>(input, point, ws);

    chamfer_reduce_kernel<<<dim3(BM / 256), dim3(256), 0, stream>>>(ws, out);
}